// Round 3
// baseline (664.573 us; speedup 1.0000x reference)
//
#include <hip/hip_runtime.h>

#define NN 100000   // nodes
#define NE 3200000  // edges
#define NF 128      // in features
#define EM 20       // embed
#define NC 10       // classes
#define NG 64       // graphs

#define NB 782      // dst buckets of 128 nodes: ceil(100000/128)
#define CAPB 4608   // per-bucket capacity: mean 4096, sigma 64, +8 sigma
#define T 4096      // edges per scatter block
#define SBLK 256    // scatter block threads

// ---------------- bucketed counting-sort scatter ----------------
// Block-local counting sort of 4096 edges by dst-bucket, then coalesced
// run-flush into per-bucket global segments (one returning atomic per
// (block,bucket) instead of per edge; writes become ~42B contiguous runs).
__global__ void k_scatter(const int* __restrict__ src, const int* __restrict__ dst,
                          const float* __restrict__ w, int* __restrict__ gcursor,
                          uint2* __restrict__ barr) {
    __shared__ unsigned int cnt[NB];
    __shared__ unsigned int off[NB];
    __shared__ unsigned int gbase[NB];
    __shared__ unsigned int scratch[1024];
    __shared__ uint2 staged[T];
    __shared__ unsigned short bkt[T];
    int tid = threadIdx.x;
    long E0 = (long)blockIdx.x * T;
    int tot = (int)min((long)T, (long)NE - E0);
    // p1: zero
    for (int i = tid; i < NB; i += SBLK) cnt[i] = 0;
    for (int i = tid; i < 1024; i += SBLK) scratch[i] = 0;
    __syncthreads();
    // p2: histogram
    for (int k = 0; k < T / SBLK; ++k) {
        int e = k * SBLK + tid;
        if (e < tot) atomicAdd(&cnt[((unsigned)dst[E0 + e]) >> 7], 1u);
    }
    __syncthreads();
    // p3: inclusive scan over 1024-padded counts (Hillis-Steele)
    for (int i = tid; i < NB; i += SBLK) scratch[i] = cnt[i];
    __syncthreads();
    for (int d = 1; d < 1024; d <<= 1) {
        unsigned int v[4];
#pragma unroll
        for (int q = 0; q < 4; ++q) {
            int idx = q * SBLK + tid;
            v[q] = (idx >= d) ? scratch[idx - d] : 0u;
        }
        __syncthreads();
#pragma unroll
        for (int q = 0; q < 4; ++q) scratch[q * SBLK + tid] += v[q];
        __syncthreads();
    }
    for (int i = tid; i < NB; i += SBLK) off[i] = scratch[i] - cnt[i];  // exclusive
    __syncthreads();
    // p4: reserve global segments; reset cnt for reuse as running offset
    for (int i = tid; i < NB; i += SBLK) {
        unsigned int c = cnt[i];
        gbase[i] = c ? (unsigned int)atomicAdd(&gcursor[i], (int)c) : 0u;
        cnt[i] = 0;
    }
    __syncthreads();
    // p5: stage records grouped by bucket
    for (int k = 0; k < T / SBLK; ++k) {
        int e = k * SBLK + tid;
        if (e < tot) {
            long ge = E0 + e;
            unsigned int d = (unsigned)dst[ge];
            unsigned int b = d >> 7;
            unsigned int slot = atomicAdd(&cnt[b], 1u);
            unsigned int pos = off[b] + slot;
            staged[pos] = make_uint2((((unsigned)src[ge]) << 7) | (d & 127u),
                                     __float_as_uint(w[ge]));
            bkt[pos] = (unsigned short)b;
        }
    }
    __syncthreads();
    // p6: coalesced run-flush
    for (int i = tid; i < tot; i += SBLK) {
        unsigned int b = bkt[i];
        unsigned int gpos = gbase[b] + ((unsigned)i - off[b]);
        if (gpos < CAPB) barr[(size_t)b * CAPB + gpos] = staged[i];
    }
}

// ---------------- per-bucket weighted degree -> dinv ----------------
__global__ void k_degb(const int* __restrict__ gcursor, const uint2* __restrict__ barr,
                       float* __restrict__ dinv) {
    __shared__ float dacc[128];
    int b = blockIdx.x, tid = threadIdx.x;
    if (tid < 128) dacc[tid] = 0.f;
    __syncthreads();
    int cntb = min(gcursor[b], CAPB);
    const uint2* row = barr + (size_t)b * CAPB;
    for (int i = tid; i < cntb; i += 256) {
        uint2 r = row[i];
        atomicAdd(&dacc[r.x & 127u], __uint_as_float(r.y));
    }
    __syncthreads();
    if (tid < 128) {
        int gd = b * 128 + tid;
        if (gd < NN) dinv[gd] = rsqrtf(1.0f + dacc[tid]);  // +1 = self-loop
    }
}

// ---------------- xw = x @ W, LDS-tiled ----------------
__global__ void k_xw(const float* __restrict__ x, const float* __restrict__ W,
                     float* __restrict__ xw) {
    __shared__ float xs[64 * 129];
    __shared__ float Ws[NF * EM];
    int base = blockIdx.x * 64;
    for (int i = threadIdx.x; i < NF * EM; i += 256) Ws[i] = W[i];
    const float4* xg = (const float4*)(x + (size_t)base * NF);
    for (int v = threadIdx.x; v < 64 * NF / 4; v += 256) {
        int fidx = v * 4;
        size_t gidx = (size_t)base * NF + fidx;
        float4 val = (gidx + 3 < (size_t)NN * NF) ? xg[v] : make_float4(0.f, 0.f, 0.f, 0.f);
        int r = fidx / NF, c = fidx % NF;
        float* p = xs + r * 129 + c;
        p[0] = val.x; p[1] = val.y; p[2] = val.z; p[3] = val.w;
    }
    __syncthreads();
    int n = threadIdx.x & 63;
    int j0 = (threadIdx.x >> 6) * 5;
    if (base + n >= NN) return;
    float acc[5] = {0.f, 0.f, 0.f, 0.f, 0.f};
    const float* xr = xs + n * 129;
#pragma unroll 4
    for (int k = 0; k < NF; ++k) {
        float xv = xr[k];
        const float* wr = Ws + k * EM + j0;
#pragma unroll
        for (int jj = 0; jj < 5; ++jj) acc[jj] = fmaf(xv, wr[jj], acc[jj]);
    }
    float* o = xw + (size_t)(base + n) * EM + j0;
#pragma unroll
    for (int jj = 0; jj < 5; ++jj) o[jj] = acc[jj];
}

// ---------------- per-bucket aggregate + bias + L2norm + ReLU ----------------
__global__ void k_aggr(const int* __restrict__ gcursor, const uint2* __restrict__ barr,
                       const float* __restrict__ dinv, const float* __restrict__ xw,
                       const float* __restrict__ b, float* __restrict__ embed) {
    __shared__ float acc[128 * EM];
    int bk = blockIdx.x, tid = threadIdx.x;
    for (int i = tid; i < 128 * EM; i += 256) acc[i] = 0.f;
    __syncthreads();
    int cntb = min(gcursor[bk], CAPB);
    const uint2* row = barr + (size_t)bk * CAPB;
    for (int i = tid; i < cntb; i += 256) {
        uint2 r = row[i];
        unsigned int s = r.x >> 7;
        unsigned int dl = r.x & 127u;
        float nw = dinv[s] * __uint_as_float(r.y);
        const float4* v = (const float4*)(xw + (size_t)s * EM);
        float* a = acc + dl * EM;
#pragma unroll
        for (int c = 0; c < 5; ++c) {
            float4 vv = v[c];
            atomicAdd(a + c * 4 + 0, vv.x * nw);
            atomicAdd(a + c * 4 + 1, vv.y * nw);
            atomicAdd(a + c * 4 + 2, vv.z * nw);
            atomicAdd(a + c * 4 + 3, vv.w * nw);
        }
    }
    __syncthreads();
    if (tid < 128) {
        int gd = bk * 128 + tid;
        if (gd < NN) {
            float dv = dinv[gd];
            const float* xd = xw + (size_t)gd * EM;
            const float* a = acc + tid * EM;
            float r[EM];
            float ss = 0.f;
#pragma unroll
            for (int j = 0; j < EM; ++j) {
                r[j] = dv * fmaf(xd[j], dv, a[j]) + b[j];
                ss = fmaf(r[j], r[j], ss);
            }
            float inv = 1.0f / fmaxf(sqrtf(ss), 1e-12f);
            float* o = embed + (size_t)gd * EM;
#pragma unroll
            for (int j = 0; j < EM; ++j) {
                float e = r[j] * inv;
                o[j] = e > 0.f ? e : 0.f;
            }
        }
    }
}

// ---------------- graph boundaries (batch sorted) ----------------
__global__ void k_bound(const int* __restrict__ batch, int* __restrict__ gstart) {
    int n = blockIdx.x * 256 + threadIdx.x;
    if (n >= NN) return;
    int bn = batch[n];
    if (n == 0) {
        for (int g = 0; g <= bn; ++g) gstart[g] = 0;
    } else {
        int bp = batch[n - 1];
        for (int g = bp + 1; g <= bn; ++g) gstart[g] = n;
    }
    if (n == NN - 1) {
        for (int g = bn + 1; g <= NG; ++g) gstart[g] = NN;
    }
}

// ---------------- per-graph pool (max+mean) + final linear ----------------
__global__ void k_poolfinal(const float* __restrict__ embed, const int* __restrict__ gstart,
                            const float* __restrict__ lw, const float* __restrict__ lb,
                            float* __restrict__ out) {
    __shared__ float cross[4][40];
    __shared__ float pooled[40];
    int g = blockIdx.x;
    int s0 = gstart[g], s1 = gstart[g + 1];
    int cnt = s1 - s0;
    float mx[EM], sm[EM];
#pragma unroll
    for (int j = 0; j < EM; ++j) { mx[j] = 0.f; sm[j] = 0.f; }
    for (int n = s0 + threadIdx.x; n < s1; n += 256) {
        const float4* e = (const float4*)(embed + (size_t)n * EM);
#pragma unroll
        for (int c = 0; c < 5; ++c) {
            float4 v = e[c];
            int j = c * 4;
            mx[j+0] = fmaxf(mx[j+0], v.x); sm[j+0] += v.x;
            mx[j+1] = fmaxf(mx[j+1], v.y); sm[j+1] += v.y;
            mx[j+2] = fmaxf(mx[j+2], v.z); sm[j+2] += v.z;
            mx[j+3] = fmaxf(mx[j+3], v.w); sm[j+3] += v.w;
        }
    }
#pragma unroll
    for (int o = 32; o > 0; o >>= 1) {
#pragma unroll
        for (int j = 0; j < EM; ++j) {
            mx[j] = fmaxf(mx[j], __shfl_xor(mx[j], o));
            sm[j] += __shfl_xor(sm[j], o);
        }
    }
    int wave = threadIdx.x >> 6, lane = threadIdx.x & 63;
    if (lane == 0) {
#pragma unroll
        for (int j = 0; j < EM; ++j) { cross[wave][j] = mx[j]; cross[wave][EM + j] = sm[j]; }
    }
    __syncthreads();
    if (threadIdx.x < 40) {
        int j = threadIdx.x;
        float v = cross[0][j];
        if (j < EM) v = fmaxf(fmaxf(v, cross[1][j]), fmaxf(cross[2][j], cross[3][j]));
        else        v = v + cross[1][j] + cross[2][j] + cross[3][j];
        if (j >= EM) v *= 1.0f / fmaxf((float)cnt, 1.0f);
        pooled[j] = v;
    }
    __syncthreads();
    if (threadIdx.x < NC) {
        int c = threadIdx.x;
        float acc = lb[c];
#pragma unroll
        for (int j = 0; j < 2 * EM; ++j) acc = fmaf(pooled[j], lw[j * NC + c], acc);
        out[g * NC + c] = acc;
    }
}

extern "C" void kernel_launch(void* const* d_in, const int* in_sizes, int n_in,
                              void* d_out, int out_size, void* d_ws, size_t ws_size,
                              hipStream_t stream) {
    const float* x     = (const float*)d_in[0];
    const int*   ei    = (const int*)d_in[1];
    const float* ew    = (const float*)d_in[2];
    const int*   batch = (const int*)d_in[3];
    const float* W     = (const float*)d_in[4];
    const float* b     = (const float*)d_in[5];
    const float* lw    = (const float*)d_in[6];
    const float* lb    = (const float*)d_in[7];
    float* out = (float*)d_out;

    char* ws = (char*)d_ws;
    int*   gcursor = (int*)ws;     ws += 4096;                    // 1024 ints (padded, 16B-aligned)
    int*   gstart  = (int*)ws;     ws += 1024;                    // 256 ints (padded)
    float* dinv    = (float*)ws;   ws += (size_t)NN * 4;          // 400000 B
    float* xw      = (float*)ws;   ws += (size_t)NN * EM * 4;     // 8 MB
    float* embed   = (float*)ws;   ws += (size_t)NN * EM * 4;     // 8 MB
    uint2* barr    = (uint2*)ws;                                  // NB*CAPB*8 = 28.8 MB

    const int* srcp = ei;
    const int* dstp = ei + NE;

    hipMemsetAsync(gcursor, 0, 4096, stream);
    k_scatter<<<(NE + T - 1) / T, SBLK, 0, stream>>>(srcp, dstp, ew, gcursor, barr);
    k_degb<<<NB, 256, 0, stream>>>(gcursor, barr, dinv);
    k_xw<<<(NN + 63) / 64, 256, 0, stream>>>(x, W, xw);
    k_aggr<<<NB, 256, 0, stream>>>(gcursor, barr, dinv, xw, b, embed);
    k_bound<<<(NN + 255) / 256, 256, 0, stream>>>(batch, gstart);
    k_poolfinal<<<NG, 256, 0, stream>>>(embed, gstart, lw, lb, out);
}

// Round 4
// 650.467 us; speedup vs baseline: 1.0217x; 1.0217x over previous
//
#include <hip/hip_runtime.h>

#define NN 100000   // nodes
#define NE 3200000  // edges
#define NF 128      // in features
#define EM 20       // embed
#define NC 10       // classes
#define NG 64       // graphs

#define NB 782      // dst buckets of 128 nodes: ceil(100000/128)
#define CAPB 4608   // per-bucket capacity: mean 4096, sigma 64, +8 sigma
#define T 4096      // edges per scatter block
#define SBLK 512    // scatter block threads

// ---------------- bucketed counting-sort scatter ----------------
__global__ void k_scatter(const int* __restrict__ src, const int* __restrict__ dst,
                          const float* __restrict__ w, int* __restrict__ gcursor,
                          uint2* __restrict__ barr) {
    __shared__ unsigned int cnt[NB];
    __shared__ unsigned int off[NB];
    __shared__ unsigned int gbase[NB];
    __shared__ uint2 staged[T];                 // also aliased as scan scratch (disjoint phases)
    __shared__ unsigned short bkt[T];
    unsigned int* scratch = (unsigned int*)staged;  // 1024 uints = first 4KB of staged
    int tid = threadIdx.x;
    long E0 = (long)blockIdx.x * T;
    int tot = (int)min((long)T, (long)NE - E0);
    // p1: zero
    for (int i = tid; i < NB; i += SBLK) cnt[i] = 0;
    for (int i = tid; i < 1024; i += SBLK) scratch[i] = 0;
    __syncthreads();
    // p2: histogram
    for (int k = 0; k < T / SBLK; ++k) {
        int e = k * SBLK + tid;
        if (e < tot) atomicAdd(&cnt[((unsigned)dst[E0 + e]) >> 7], 1u);
    }
    __syncthreads();
    // p3: inclusive scan over 1024-padded counts (Hillis-Steele)
    for (int i = tid; i < NB; i += SBLK) scratch[i] = cnt[i];
    __syncthreads();
    for (int d = 1; d < 1024; d <<= 1) {
        unsigned int v[1024 / SBLK];
#pragma unroll
        for (int q = 0; q < 1024 / SBLK; ++q) {
            int idx = q * SBLK + tid;
            v[q] = (idx >= d) ? scratch[idx - d] : 0u;
        }
        __syncthreads();
#pragma unroll
        for (int q = 0; q < 1024 / SBLK; ++q) scratch[q * SBLK + tid] += v[q];
        __syncthreads();
    }
    for (int i = tid; i < NB; i += SBLK) off[i] = scratch[i] - cnt[i];  // exclusive
    __syncthreads();
    // p4: reserve global segments; reset cnt for reuse as running slot counter
    for (int i = tid; i < NB; i += SBLK) {
        unsigned int c = cnt[i];
        gbase[i] = c ? (unsigned int)atomicAdd(&gcursor[i], (int)c) : 0u;
        cnt[i] = 0;
    }
    __syncthreads();   // scratch (== staged) no longer needed past here
    // p5: stage records grouped by bucket
    for (int k = 0; k < T / SBLK; ++k) {
        int e = k * SBLK + tid;
        if (e < tot) {
            long ge = E0 + e;
            unsigned int d = (unsigned)dst[ge];
            unsigned int b = d >> 7;
            unsigned int slot = atomicAdd(&cnt[b], 1u);
            unsigned int pos = off[b] + slot;
            staged[pos] = make_uint2((((unsigned)src[ge]) << 7) | (d & 127u),
                                     __float_as_uint(w[ge]));
            bkt[pos] = (unsigned short)b;
        }
    }
    __syncthreads();
    // p6: coalesced run-flush
    for (int i = tid; i < tot; i += SBLK) {
        unsigned int b = bkt[i];
        unsigned int gpos = gbase[b] + ((unsigned)i - off[b]);
        if (gpos < CAPB) barr[(size_t)b * CAPB + gpos] = staged[i];
    }
}

// ---------------- per-bucket weighted degree -> dinv ----------------
__global__ void k_degb(const int* __restrict__ gcursor, const uint2* __restrict__ barr,
                       float* __restrict__ dinv) {
    __shared__ float dacc[128];
    int b = blockIdx.x, tid = threadIdx.x;
    if (tid < 128) dacc[tid] = 0.f;
    __syncthreads();
    int cntb = min(gcursor[b], CAPB);
    const uint2* row = barr + (size_t)b * CAPB;
    for (int i = tid; i < cntb; i += 1024) {
        uint2 r = row[i];
        atomicAdd(&dacc[r.x & 127u], __uint_as_float(r.y));
    }
    __syncthreads();
    if (tid < 128) {
        int gd = b * 128 + tid;
        if (gd < NN) dinv[gd] = rsqrtf(1.0f + dacc[tid]);  // +1 = self-loop
    }
}

// ---------------- xw = x @ W, LDS-tiled ----------------
__global__ void k_xw(const float* __restrict__ x, const float* __restrict__ W,
                     float* __restrict__ xw) {
    __shared__ float xs[64 * 129];
    __shared__ float Ws[NF * EM];
    int base = blockIdx.x * 64;
    for (int i = threadIdx.x; i < NF * EM; i += 256) Ws[i] = W[i];
    const float4* xg = (const float4*)(x + (size_t)base * NF);
    for (int v = threadIdx.x; v < 64 * NF / 4; v += 256) {
        int fidx = v * 4;
        size_t gidx = (size_t)base * NF + fidx;
        float4 val = (gidx + 3 < (size_t)NN * NF) ? xg[v] : make_float4(0.f, 0.f, 0.f, 0.f);
        int r = fidx / NF, c = fidx % NF;
        float* p = xs + r * 129 + c;
        p[0] = val.x; p[1] = val.y; p[2] = val.z; p[3] = val.w;
    }
    __syncthreads();
    int n = threadIdx.x & 63;
    int j0 = (threadIdx.x >> 6) * 5;
    if (base + n >= NN) return;
    float acc[5] = {0.f, 0.f, 0.f, 0.f, 0.f};
    const float* xr = xs + n * 129;
#pragma unroll 4
    for (int k = 0; k < NF; ++k) {
        float xv = xr[k];
        const float* wr = Ws + k * EM + j0;
#pragma unroll
        for (int jj = 0; jj < 5; ++jj) acc[jj] = fmaf(xv, wr[jj], acc[jj]);
    }
    float* o = xw + (size_t)(base + n) * EM + j0;
#pragma unroll
    for (int jj = 0; jj < 5; ++jj) o[jj] = acc[jj];
}

// ---------------- per-bucket aggregate + bias + L2norm + ReLU ----------------
__global__ void k_aggr(const int* __restrict__ gcursor, const uint2* __restrict__ barr,
                       const float* __restrict__ dinv, const float* __restrict__ xw,
                       const float* __restrict__ b, float* __restrict__ embed) {
    __shared__ float acc[128 * EM];
    int bk = blockIdx.x, tid = threadIdx.x;
    for (int i = tid; i < 128 * EM; i += 1024) acc[i] = 0.f;
    __syncthreads();
    int cntb = min(gcursor[bk], CAPB);
    const uint2* row = barr + (size_t)bk * CAPB;
    for (int i = tid; i < cntb; i += 1024) {
        uint2 r = row[i];
        unsigned int s = r.x >> 7;
        unsigned int dl = r.x & 127u;
        float nw = dinv[s] * __uint_as_float(r.y);
        const float4* v = (const float4*)(xw + (size_t)s * EM);
        float* a = acc + dl * EM;
#pragma unroll
        for (int c = 0; c < 5; ++c) {
            float4 vv = v[c];
            atomicAdd(a + c * 4 + 0, vv.x * nw);
            atomicAdd(a + c * 4 + 1, vv.y * nw);
            atomicAdd(a + c * 4 + 2, vv.z * nw);
            atomicAdd(a + c * 4 + 3, vv.w * nw);
        }
    }
    __syncthreads();
    if (tid < 128) {
        int gd = bk * 128 + tid;
        if (gd < NN) {
            float dv = dinv[gd];
            const float* xd = xw + (size_t)gd * EM;
            const float* a = acc + tid * EM;
            float r[EM];
            float ss = 0.f;
#pragma unroll
            for (int j = 0; j < EM; ++j) {
                r[j] = dv * fmaf(xd[j], dv, a[j]) + b[j];
                ss = fmaf(r[j], r[j], ss);
            }
            float inv = 1.0f / fmaxf(sqrtf(ss), 1e-12f);
            float* o = embed + (size_t)gd * EM;
#pragma unroll
            for (int j = 0; j < EM; ++j) {
                float e = r[j] * inv;
                o[j] = e > 0.f ? e : 0.f;
            }
        }
    }
}

// ---------------- graph boundaries (batch sorted) ----------------
__global__ void k_bound(const int* __restrict__ batch, int* __restrict__ gstart) {
    int n = blockIdx.x * 256 + threadIdx.x;
    if (n >= NN) return;
    int bn = batch[n];
    if (n == 0) {
        for (int g = 0; g <= bn; ++g) gstart[g] = 0;
    } else {
        int bp = batch[n - 1];
        for (int g = bp + 1; g <= bn; ++g) gstart[g] = n;
    }
    if (n == NN - 1) {
        for (int g = bn + 1; g <= NG; ++g) gstart[g] = NN;
    }
}

// ---------------- per-graph pool (max+mean) + final linear ----------------
__global__ void k_poolfinal(const float* __restrict__ embed, const int* __restrict__ gstart,
                            const float* __restrict__ lw, const float* __restrict__ lb,
                            float* __restrict__ out) {
    __shared__ float cross[4][40];
    __shared__ float pooled[40];
    int g = blockIdx.x;
    int s0 = gstart[g], s1 = gstart[g + 1];
    int cnt = s1 - s0;
    float mx[EM], sm[EM];
#pragma unroll
    for (int j = 0; j < EM; ++j) { mx[j] = 0.f; sm[j] = 0.f; }
    for (int n = s0 + threadIdx.x; n < s1; n += 256) {
        const float4* e = (const float4*)(embed + (size_t)n * EM);
#pragma unroll
        for (int c = 0; c < 5; ++c) {
            float4 v = e[c];
            int j = c * 4;
            mx[j+0] = fmaxf(mx[j+0], v.x); sm[j+0] += v.x;
            mx[j+1] = fmaxf(mx[j+1], v.y); sm[j+1] += v.y;
            mx[j+2] = fmaxf(mx[j+2], v.z); sm[j+2] += v.z;
            mx[j+3] = fmaxf(mx[j+3], v.w); sm[j+3] += v.w;
        }
    }
#pragma unroll
    for (int o = 32; o > 0; o >>= 1) {
#pragma unroll
        for (int j = 0; j < EM; ++j) {
            mx[j] = fmaxf(mx[j], __shfl_xor(mx[j], o));
            sm[j] += __shfl_xor(sm[j], o);
        }
    }
    int wave = threadIdx.x >> 6, lane = threadIdx.x & 63;
    if (lane == 0) {
#pragma unroll
        for (int j = 0; j < EM; ++j) { cross[wave][j] = mx[j]; cross[wave][EM + j] = sm[j]; }
    }
    __syncthreads();
    if (threadIdx.x < 40) {
        int j = threadIdx.x;
        float v = cross[0][j];
        if (j < EM) v = fmaxf(fmaxf(v, cross[1][j]), fmaxf(cross[2][j], cross[3][j]));
        else        v = v + cross[1][j] + cross[2][j] + cross[3][j];
        if (j >= EM) v *= 1.0f / fmaxf((float)cnt, 1.0f);
        pooled[j] = v;
    }
    __syncthreads();
    if (threadIdx.x < NC) {
        int c = threadIdx.x;
        float acc = lb[c];
#pragma unroll
        for (int j = 0; j < 2 * EM; ++j) acc = fmaf(pooled[j], lw[j * NC + c], acc);
        out[g * NC + c] = acc;
    }
}

extern "C" void kernel_launch(void* const* d_in, const int* in_sizes, int n_in,
                              void* d_out, int out_size, void* d_ws, size_t ws_size,
                              hipStream_t stream) {
    const float* x     = (const float*)d_in[0];
    const int*   ei    = (const int*)d_in[1];
    const float* ew    = (const float*)d_in[2];
    const int*   batch = (const int*)d_in[3];
    const float* W     = (const float*)d_in[4];
    const float* b     = (const float*)d_in[5];
    const float* lw    = (const float*)d_in[6];
    const float* lb    = (const float*)d_in[7];
    float* out = (float*)d_out;

    char* ws = (char*)d_ws;
    int*   gcursor = (int*)ws;     ws += 4096;
    int*   gstart  = (int*)ws;     ws += 1024;
    float* dinv    = (float*)ws;   ws += (size_t)NN * 4;
    float* xw      = (float*)ws;   ws += (size_t)NN * EM * 4;
    float* embed   = (float*)ws;   ws += (size_t)NN * EM * 4;
    uint2* barr    = (uint2*)ws;   // NB*CAPB*8 = 28.8 MB

    const int* srcp = ei;
    const int* dstp = ei + NE;

    hipMemsetAsync(gcursor, 0, 4096, stream);
    k_scatter<<<(NE + T - 1) / T, SBLK, 0, stream>>>(srcp, dstp, ew, gcursor, barr);
    k_degb<<<NB, 1024, 0, stream>>>(gcursor, barr, dinv);
    k_xw<<<(NN + 63) / 64, 256, 0, stream>>>(x, W, xw);
    k_aggr<<<NB, 1024, 0, stream>>>(gcursor, barr, dinv, xw, b, embed);
    k_bound<<<(NN + 255) / 256, 256, 0, stream>>>(batch, gstart);
    k_poolfinal<<<NG, 256, 0, stream>>>(embed, gstart, lw, lb, out);
}